// Round 3
// baseline (329.440 us; speedup 1.0000x reference)
//
#include <hip/hip_runtime.h>
#include <hip/hip_bf16.h>

// f32 in/out. Internal: bf16 MFMA, W split hi/lo (2-term), A rounded to bf16.
// Tolerance 0.02*max|ref| ~= 0.028; measured r2 (3-term) = 0.0078.
typedef __bf16 bf16;
typedef __bf16 bf16x8 __attribute__((ext_vector_type(8)));
typedef float  f32x4  __attribute__((ext_vector_type(4)));

#define DEVINL __device__ __forceinline__

DEVINL void gll16(const void* g, void* l) {
  __builtin_amdgcn_global_load_lds(
      (const __attribute__((address_space(1))) unsigned int*)g,
      (__attribute__((address_space(3))) unsigned int*)l, 16, 0, 0);
}

DEVINL bf16x8 cvt_hi(const float4& a, const float4& b) {
  bf16x8 h;
  h[0] = (bf16)a.x; h[1] = (bf16)a.y; h[2] = (bf16)a.z; h[3] = (bf16)a.w;
  h[4] = (bf16)b.x; h[5] = (bf16)b.y; h[6] = (bf16)b.z; h[7] = (bf16)b.w;
  return h;
}

// ---------------------------------------------------------------------------
// Weight prep: W[k][n] f32 -> Wt_hi[n][k], Wt_lo[n][k] bf16 (transposed+split).
// ---------------------------------------------------------------------------
__global__ void k_prep(const float* __restrict__ Wq, const float* __restrict__ Wk,
                       const float* __restrict__ Wv, const float* __restrict__ Wo,
                       bf16* __restrict__ wtq_h, bf16* __restrict__ wtq_l,
                       bf16* __restrict__ wtkv_h, bf16* __restrict__ wtkv_l,
                       bf16* __restrict__ wto_h, bf16* __restrict__ wto_l) {
  const int k = blockIdx.x;
  const int n = threadIdx.x;
  const int m = blockIdx.y;
  const float* src = (m == 0) ? Wq : (m == 1) ? Wk : (m == 2) ? Wv : Wo;
  bf16* dh = (m == 0) ? wtq_h : (m == 3) ? wto_h : (m == 1) ? wtkv_h : (wtkv_h + 256 * 256);
  bf16* dl = (m == 0) ? wtq_l : (m == 3) ? wto_l : (m == 1) ? wtkv_l : (wtkv_l + 256 * 256);
  const float v = src[k * 256 + n];
  const bf16 h = (bf16)v;
  dh[n * 256 + k] = h;
  dl[n * 256 + k] = (bf16)(v - (float)h);
}

// ---------------------------------------------------------------------------
// Fused q/kv projection. Block: 64 rows x 128 cols, 4 waves of 32x64,
// BK=32, 8 K-iters, MFMA 16x16x32. 2-term: Ah*Wh + Ah*Wl.
// XCD swizzle: g&7 = XCD slot; siblings (same m, nb=0..5) adjacent in time
// on one XCD so the A tile is fetched from HBM once and L2-reused.
// nb 0..1: A=q -> qp cols nb*128.  nb 2..5: A=kv -> [kp|vp] cols (nb-2)*128.
// ---------------------------------------------------------------------------
__global__ __launch_bounds__(256, 4) void k_qkv(
    const float* __restrict__ q, const float* __restrict__ kv,
    const bf16* __restrict__ wtq_h, const bf16* __restrict__ wtq_l,
    const bf16* __restrict__ wtkv_h, const bf16* __restrict__ wtkv_l,
    const float* __restrict__ bq, const float* __restrict__ bk,
    const float* __restrict__ bv,
    bf16* __restrict__ qp, bf16* __restrict__ kp, bf16* __restrict__ vp) {
  __shared__ __align__(16) bf16 Ash[64 * 32];    // 4 KB
  __shared__ __align__(16) bf16 Bsh[128 * 32];   // 8 KB
  __shared__ __align__(16) bf16 Bsl[128 * 32];   // 8 KB

  const int g = blockIdx.x;
  const int xcd = g & 7;
  const int s = g >> 3;
  const int nb = s % 6;
  const int mh = s / 6;
  const int m0 = (mh * 8 + xcd) * 64;

  const bool isq = (nb < 2);
  const float* A = isq ? q : kv;
  const bf16* Wh = isq ? wtq_h : wtkv_h;
  const bf16* Wl = isq ? wtq_l : wtkv_l;
  const int n0 = isq ? nb * 128 : (nb - 2) * 128;

  const int tid = threadIdx.x;
  const int lane = tid & 63;
  const int wave = tid >> 6;
  const int mw = (wave >> 1) * 32;
  const int nw = (wave & 1) * 64;
  const int lm = lane & 15;
  const int lq = lane >> 4;

  f32x4 acc[2][4];
#pragma unroll
  for (int i = 0; i < 2; ++i)
#pragma unroll
    for (int j = 0; j < 4; ++j) acc[i][j] = (f32x4)0.0f;

  // B staging: 512 chunks of 16B per matrix; 2 per thread.
  const int rB0 = tid >> 2, oB0 = (tid & 3) * 8;           // chunk tid
  const int rB1 = (tid + 256) >> 2, oB1 = oB0;             // chunk tid+256
  // A staging (f32): 8 floats per thread.
  const int rowA = tid >> 2;
  const int qA = (tid & 3) * 8;

  for (int k0 = 0; k0 < 256; k0 += 32) {
    gll16(Wh + (size_t)(n0 + rB0) * 256 + k0 + oB0, &Bsh[tid * 8]);
    gll16(Wh + (size_t)(n0 + rB1) * 256 + k0 + oB1, &Bsh[(tid + 256) * 8]);
    gll16(Wl + (size_t)(n0 + rB0) * 256 + k0 + oB0, &Bsl[tid * 8]);
    gll16(Wl + (size_t)(n0 + rB1) * 256 + k0 + oB1, &Bsl[(tid + 256) * 8]);

    const float* src = A + (size_t)(m0 + rowA) * 256 + k0 + qA;
    const float4 f0 = *(const float4*)(src);
    const float4 f1 = *(const float4*)(src + 4);
    *(bf16x8*)&Ash[rowA * 32 + qA] = cvt_hi(f0, f1);
    __syncthreads();

    bf16x8 av[2], bh[4], bl[4];
#pragma unroll
    for (int t = 0; t < 2; ++t)
      av[t] = *(const bf16x8*)&Ash[(mw + t * 16 + lm) * 32 + lq * 8];
#pragma unroll
    for (int j = 0; j < 4; ++j) {
      bh[j] = *(const bf16x8*)&Bsh[(nw + j * 16 + lm) * 32 + lq * 8];
      bl[j] = *(const bf16x8*)&Bsl[(nw + j * 16 + lm) * 32 + lq * 8];
    }
#pragma unroll
    for (int i = 0; i < 2; ++i)
#pragma unroll
      for (int j = 0; j < 4; ++j) {
        acc[i][j] = __builtin_amdgcn_mfma_f32_16x16x32_bf16(av[i], bh[j], acc[i][j], 0, 0, 0);
        acc[i][j] = __builtin_amdgcn_mfma_f32_16x16x32_bf16(av[i], bl[j], acc[i][j], 0, 0, 0);
      }
    __syncthreads();
  }

  // Epilogue. C layout: col = lane&15, row = (lane>>4)*4 + reg.
#pragma unroll
  for (int i = 0; i < 2; ++i) {
#pragma unroll
    for (int j = 0; j < 4; ++j) {
      const int n_g = n0 + nw + j * 16 + lm;   // q: 0..255; kv: 0..511
      bf16* op;
      float bval;
      int nc;
      if (isq) {
        op = qp; nc = n_g; bval = bq[n_g];
      } else if (n_g < 256) {
        op = kp; nc = n_g; bval = bk[n_g];
      } else {
        op = vp; nc = n_g - 256; bval = bv[n_g - 256];
      }
#pragma unroll
      for (int r = 0; r < 4; ++r) {
        const int m_g = m0 + mw + i * 16 + lq * 4 + r;
        op[(size_t)m_g * 256 + nc] = (bf16)(acc[i][j][r] + bval);
      }
    }
  }
}

// ---------------------------------------------------------------------------
// Output projection: A = ao (bf16), W = wto hi/lo, out f32. Same tiling.
// ---------------------------------------------------------------------------
__global__ __launch_bounds__(256, 4) void k_oproj(
    const bf16* __restrict__ A, const bf16* __restrict__ Wh,
    const bf16* __restrict__ Wl, const float* __restrict__ bias,
    float* __restrict__ out) {
  __shared__ __align__(16) bf16 Ash[64 * 32];
  __shared__ __align__(16) bf16 Bsh[128 * 32];
  __shared__ __align__(16) bf16 Bsl[128 * 32];

  const int g = blockIdx.x;
  const int xcd = g & 7;
  const int s = g >> 3;
  const int nb = s & 1;
  const int mh = s >> 1;
  const int m0 = (mh * 8 + xcd) * 64;
  const int n0 = nb * 128;

  const int tid = threadIdx.x;
  const int lane = tid & 63;
  const int wave = tid >> 6;
  const int mw = (wave >> 1) * 32;
  const int nw = (wave & 1) * 64;
  const int lm = lane & 15;
  const int lq = lane >> 4;

  f32x4 acc[2][4];
#pragma unroll
  for (int i = 0; i < 2; ++i)
#pragma unroll
    for (int j = 0; j < 4; ++j) acc[i][j] = (f32x4)0.0f;

  const int rB0 = tid >> 2, oB0 = (tid & 3) * 8;
  const int rB1 = (tid + 256) >> 2;

  for (int k0 = 0; k0 < 256; k0 += 32) {
    gll16(Wh + (size_t)(n0 + rB0) * 256 + k0 + oB0, &Bsh[tid * 8]);
    gll16(Wh + (size_t)(n0 + rB1) * 256 + k0 + oB0, &Bsh[(tid + 256) * 8]);
    gll16(Wl + (size_t)(n0 + rB0) * 256 + k0 + oB0, &Bsl[tid * 8]);
    gll16(Wl + (size_t)(n0 + rB1) * 256 + k0 + oB0, &Bsl[(tid + 256) * 8]);
    // A: 64x32 bf16 = 256 chunks of 16B; 1 per thread (chunk = tid).
    gll16(A + (size_t)(m0 + rB0) * 256 + k0 + oB0, &Ash[tid * 8]);
    __syncthreads();

    bf16x8 av[2], bh[4], bl[4];
#pragma unroll
    for (int t = 0; t < 2; ++t)
      av[t] = *(const bf16x8*)&Ash[(mw + t * 16 + lm) * 32 + lq * 8];
#pragma unroll
    for (int j = 0; j < 4; ++j) {
      bh[j] = *(const bf16x8*)&Bsh[(nw + j * 16 + lm) * 32 + lq * 8];
      bl[j] = *(const bf16x8*)&Bsl[(nw + j * 16 + lm) * 32 + lq * 8];
    }
#pragma unroll
    for (int i = 0; i < 2; ++i)
#pragma unroll
      for (int j = 0; j < 4; ++j) {
        acc[i][j] = __builtin_amdgcn_mfma_f32_16x16x32_bf16(av[i], bh[j], acc[i][j], 0, 0, 0);
        acc[i][j] = __builtin_amdgcn_mfma_f32_16x16x32_bf16(av[i], bl[j], acc[i][j], 0, 0, 0);
      }
    __syncthreads();
  }

#pragma unroll
  for (int i = 0; i < 2; ++i) {
#pragma unroll
    for (int j = 0; j < 4; ++j) {
      const int n_g = n0 + nw + j * 16 + lm;
      const float bval = bias[n_g];
#pragma unroll
      for (int r = 0; r < 4; ++r) {
        const int m_g = m0 + mw + i * 16 + lq * 4 + r;
        out[(size_t)m_g * 256 + n_g] = acc[i][j][r] + bval;
      }
    }
  }
}

// ---------------------------------------------------------------------------
// Windowed attention (unchanged from r2 — correct; optimize next round).
// ---------------------------------------------------------------------------
__global__ __launch_bounds__(256) void k_attn(
    const bf16* __restrict__ qp, const bf16* __restrict__ kp,
    const bf16* __restrict__ vp, bf16* __restrict__ ao) {
  __shared__ __align__(16) bf16 smem[3 * 64 * 136];
  bf16* Qs = smem;
  bf16* Ks = smem + 64 * 136;
  bf16* Vs = smem + 2 * 64 * 136;
  bf16* Ps = smem;
  bf16* Os = Vs;

  const int tid = threadIdx.x;
  const int lane = tid & 63;
  const int hl = tid >> 6;
  const int bw = blockIdx.x;
  const int b = bw >> 8;
  const int w = bw & 255;
  const int wy = w >> 4, wx = w & 15;
  const int ch0 = blockIdx.y * 128;

#pragma unroll
  for (int i = 0; i < 4; ++i) {
    const int c = i * 256 + tid;
    const int t = c >> 4;
    const int off = (c & 15) * 8;
    const int ty = t >> 3, tx = t & 7;
    const size_t gr = ((size_t)(b * 128 + wy * 8 + ty)) * 128 + wx * 8 + tx;
    const size_t gi = gr * 256 + ch0 + off;
    const int li = t * 136 + off;
    *(uint4*)&Qs[li] = *(const uint4*)&qp[gi];
    *(uint4*)&Ks[li] = *(const uint4*)&kp[gi];
    *(uint4*)&Vs[li] = *(const uint4*)&vp[gi];
  }
  __syncthreads();

  const int chh = hl * 32;
  const int lm = lane & 15;
  const int lq = lane >> 4;

  bf16x8 qa[4], kb[4];
#pragma unroll
  for (int t = 0; t < 4; ++t)
    qa[t] = *(const bf16x8*)&Qs[(t * 16 + lm) * 136 + chh + lq * 8];
#pragma unroll
  for (int t = 0; t < 4; ++t)
    kb[t] = *(const bf16x8*)&Ks[(t * 16 + lm) * 136 + chh + lq * 8];

  f32x4 s[4][4];
#pragma unroll
  for (int i = 0; i < 4; ++i)
#pragma unroll
    for (int j = 0; j < 4; ++j) s[i][j] = (f32x4)0.0f;
#pragma unroll
  for (int i = 0; i < 4; ++i)
#pragma unroll
    for (int j = 0; j < 4; ++j)
      s[i][j] = __builtin_amdgcn_mfma_f32_16x16x32_bf16(qa[i], kb[j], s[i][j], 0, 0, 0);

  const float scale = 0.17677669529663687f;
  float rl[4][4];
#pragma unroll
  for (int mt = 0; mt < 4; ++mt) {
#pragma unroll
    for (int r = 0; r < 4; ++r) {
      float mx = fmaxf(fmaxf(s[mt][0][r], s[mt][1][r]), fmaxf(s[mt][2][r], s[mt][3][r]));
      mx = fmaxf(mx, __shfl_xor(mx, 1));
      mx = fmaxf(mx, __shfl_xor(mx, 2));
      mx = fmaxf(mx, __shfl_xor(mx, 4));
      mx = fmaxf(mx, __shfl_xor(mx, 8));
      float sum = 0.f;
#pragma unroll
      for (int nt = 0; nt < 4; ++nt) {
        const float p = __expf((s[mt][nt][r] - mx) * scale);
        s[mt][nt][r] = p;
        sum += p;
      }
      sum += __shfl_xor(sum, 1);
      sum += __shfl_xor(sum, 2);
      sum += __shfl_xor(sum, 4);
      sum += __shfl_xor(sum, 8);
      rl[mt][r] = 1.0f / sum;
    }
  }

  __syncthreads();

  bf16* Ph = Ps + hl * 4096;
#pragma unroll
  for (int mt = 0; mt < 4; ++mt)
#pragma unroll
    for (int nt = 0; nt < 4; ++nt)
#pragma unroll
      for (int r = 0; r < 4; ++r) {
        const int qrow = mt * 16 + lq * 4 + r;
        const int kcol = nt * 16 + lm;
        Ph[qrow * 64 + (((kcol >> 3) ^ (qrow & 7)) << 3) + (kcol & 7)] = (bf16)s[mt][nt][r];
      }

  f32x4 o[4][2];
#pragma unroll
  for (int i = 0; i < 4; ++i) { o[i][0] = (f32x4)0.0f; o[i][1] = (f32x4)0.0f; }
#pragma unroll
  for (int ks = 0; ks < 2; ++ks) {
    bf16x8 pa[4];
#pragma unroll
    for (int mt = 0; mt < 4; ++mt) {
      const int qrow = mt * 16 + lm;
      const int gsel = ks * 4 + lq;
      pa[mt] = *(const bf16x8*)&Ph[qrow * 64 + ((gsel ^ (qrow & 7)) << 3)];
    }
    bf16x8 vbf[2];
#pragma unroll
    for (int ntd = 0; ntd < 2; ++ntd) {
      const int d = ntd * 16 + lm;
      bf16x8 tv;
#pragma unroll
      for (int j = 0; j < 8; ++j)
        tv[j] = Vs[(ks * 32 + lq * 8 + j) * 136 + chh + d];
      vbf[ntd] = tv;
    }
#pragma unroll
    for (int mt = 0; mt < 4; ++mt)
#pragma unroll
      for (int ntd = 0; ntd < 2; ++ntd)
        o[mt][ntd] = __builtin_amdgcn_mfma_f32_16x16x32_bf16(pa[mt], vbf[ntd], o[mt][ntd], 0, 0, 0);
  }

  __syncthreads();

#pragma unroll
  for (int mt = 0; mt < 4; ++mt)
#pragma unroll
    for (int ntd = 0; ntd < 2; ++ntd)
#pragma unroll
      for (int r = 0; r < 4; ++r) {
        const int qrow = mt * 16 + lq * 4 + r;
        const int d = ntd * 16 + lm;
        Os[qrow * 136 + chh + d] = (bf16)(o[mt][ntd][r] * rl[mt][r]);
      }
  __syncthreads();

#pragma unroll
  for (int i = 0; i < 4; ++i) {
    const int c = i * 256 + tid;
    const int t = c >> 4;
    const int off = (c & 15) * 8;
    const int ty = t >> 3, tx = t & 7;
    const size_t gr = ((size_t)(b * 128 + wy * 8 + ty)) * 128 + wx * 8 + tx;
    *(uint4*)&ao[gr * 256 + ch0 + off] = *(const uint4*)&Os[t * 136 + off];
  }
}

// ---------------------------------------------------------------------------
extern "C" void kernel_launch(void* const* d_in, const int* in_sizes, int n_in,
                              void* d_out, int out_size, void* d_ws, size_t ws_size,
                              hipStream_t stream) {
  const float* q  = (const float*)d_in[0];
  const float* kv = (const float*)d_in[1];
  const float* Wq = (const float*)d_in[2];
  const float* bq = (const float*)d_in[3];
  const float* Wk = (const float*)d_in[4];
  const float* bk = (const float*)d_in[5];
  const float* Wv = (const float*)d_in[6];
  const float* bv = (const float*)d_in[7];
  const float* Wo = (const float*)d_in[8];
  const float* bo = (const float*)d_in[9];
  float* out = (float*)d_out;

  char* ws = (char*)d_ws;
  bf16* wtq_h  = (bf16*)(ws + 0);
  bf16* wtq_l  = (bf16*)(ws + 131072);
  bf16* wtkv_h = (bf16*)(ws + 262144);
  bf16* wtkv_l = (bf16*)(ws + 524288);
  bf16* wto_h  = (bf16*)(ws + 786432);
  bf16* wto_l  = (bf16*)(ws + 917504);
  const size_t PLANE = (size_t)65536 * 256 * 2;
  bf16* qp = (bf16*)(ws + 1048576);
  bf16* kp = (bf16*)(ws + 1048576 + PLANE);
  bf16* vp = (bf16*)(ws + 1048576 + 2 * PLANE);
  bf16* ao = (bf16*)(ws + 1048576 + 3 * PLANE);
  if (ws_size < 1048576 + 4 * PLANE) return;

  k_prep<<<dim3(256, 4), 256, 0, stream>>>(Wq, Wk, Wv, Wo, wtq_h, wtq_l,
                                           wtkv_h, wtkv_l, wto_h, wto_l);
  // fused q + kv projections: 1024 m-blocks x 6 n-tiles, XCD-swizzled
  k_qkv<<<6144, 256, 0, stream>>>(q, kv, wtq_h, wtq_l, wtkv_h, wtkv_l,
                                  bq, bk, bv, qp, kp, vp);
  // windowed attention
  k_attn<<<dim3(1024, 2), 256, 0, stream>>>(qp, kp, vp, ao);
  // output projection: 1024 m-blocks x 2 n-tiles
  k_oproj<<<2048, 256, 0, stream>>>(ao, wto_h, wto_l, bo, out);
}

// Round 4
// 311.445 us; speedup vs baseline: 1.0578x; 1.0578x over previous
//
#include <hip/hip_runtime.h>
#include <hip/hip_bf16.h>

// f32 in/out. Internal: bf16 MFMA. q/kv projections 1-term bf16 (W hi only);
// o-proj exact 2-term via K=512 packed [Wo_hi | Wo_lo]. Weights pre-packed in
// k_prep into the exact LDS tile image consumed by global_load_lds(16B).
// Measured r2/r3 absmax 0.0078 (2-term everywhere); tolerance 0.0283.
typedef __bf16 bf16;
typedef __bf16 bf16x8 __attribute__((ext_vector_type(8)));
typedef float  f32x4  __attribute__((ext_vector_type(4)));

#define DEVINL __device__ __forceinline__

DEVINL void gll16(const void* g, void* l) {
  __builtin_amdgcn_global_load_lds(
      (const __attribute__((address_space(1))) unsigned int*)g,
      (__attribute__((address_space(3))) unsigned int*)l, 16, 0, 0);
}

// ---------------------------------------------------------------------------
// Weight pack. Tile image (per n-tile of 128, per k-iter of 64):
//   1024 slots of 16B; slot s: h=s>>9 (k-half of 32), row=(s&511)>>2, kg=s&3
//   holds W[k0 + h*32 + kg*8 + e][n0+row] for e=0..7  (transposed+bf16).
// packQ: 6 n-tiles (q:0-1, k:2-3, v:4-5) x 4 k-iters (hi only).
// packO: 2 n-tiles x 8 k-iters (iters 0-3 = Wo_hi, 4-7 = Wo_lo).
// ---------------------------------------------------------------------------
__global__ void k_prep(const float* __restrict__ Wq, const float* __restrict__ Wk,
                       const float* __restrict__ Wv, const float* __restrict__ Wo,
                       bf16* __restrict__ packQ, bf16* __restrict__ packO) {
  const int n = threadIdx.x;   // dest column 0..255
  const int k = blockIdx.x;    // source k 0..255
  const int m = blockIdx.y;    // 0:Wq 1:Wk 2:Wv 3:Wo-hi 4:Wo-lo
  const int kk = k & 63, iter4 = k >> 6;
  const int h = kk >> 5, kg = (kk >> 3) & 3, e = k & 7;
  if (m < 3) {
    const float* W = (m == 0) ? Wq : (m == 1) ? Wk : Wv;
    const bf16 v = (bf16)W[k * 256 + n];
    const int nglob = m * 256 + n;
    const int tile = nglob >> 7, row = nglob & 127;
    packQ[(size_t)((tile * 4 + iter4) * 1024 + h * 512 + row * 4 + kg) * 8 + e] = v;
  } else {
    const float w = Wo[k * 256 + n];
    const bf16 hi = (bf16)w;
    const bf16 v = (m == 3) ? hi : (bf16)(w - (float)hi);
    const int iter = (m - 3) * 4 + iter4;
    const int tile = n >> 7, row = n & 127;
    packO[(size_t)((tile * 8 + iter) * 1024 + h * 512 + row * 4 + kg) * 8 + e] = v;
  }
}

// ---------------------------------------------------------------------------
// Fused q/kv projection. 128x128 tile, BK=64 (4 iters), 4 waves of 64x64.
// 1-term bf16. B via gll16 from packQ; A (f32) cvt->bf16 in-kernel.
// XCD swizzle: 6 n-siblings of one m-tile adjacent on one XCD (A L2 reuse).
// ---------------------------------------------------------------------------
__global__ __launch_bounds__(256, 3) void k_qkv(
    const float* __restrict__ q, const float* __restrict__ kv,
    const bf16* __restrict__ packQ,
    const float* __restrict__ bq, const float* __restrict__ bk,
    const float* __restrict__ bvv,
    bf16* __restrict__ qp, bf16* __restrict__ kp, bf16* __restrict__ vp) {
  __shared__ __align__(16) bf16 As[2][128 * 32];
  __shared__ __align__(16) bf16 Bs[2][128 * 32];

  const int g = blockIdx.x, xcd = g & 7, s = g >> 3;
  const int nb = s % 6, mh = s / 6;
  const int m0 = (mh * 8 + xcd) * 128;
  const float* A = (nb < 2) ? q : kv;

  const int tid = threadIdx.x, lane = tid & 63, wave = tid >> 6;
  const int mw = (wave >> 1) * 64, nw = (wave & 1) * 64;
  const int lm = lane & 15, lq = lane >> 4;

  f32x4 acc[4][4];
#pragma unroll
  for (int a = 0; a < 4; ++a)
#pragma unroll
    for (int b = 0; b < 4; ++b) acc[a][b] = (f32x4)0.0f;

  const int rowA = tid >> 1;
  const int hA = tid & 1;
  const bf16* pbase = packQ + (size_t)nb * 4 * 8192;

  for (int i = 0; i < 4; ++i) {
    // B: 16 KB via 4 global_load_lds (dest = exact pack image)
    const bf16* pit = pbase + i * 8192;
#pragma unroll
    for (int u = 0; u < 4; ++u) {
      const int c = u * 256 + tid;
      bf16* dst = (u < 2) ? &Bs[0][c * 8] : &Bs[1][(c - 512) * 8];
      gll16(pit + c * 8, dst);
    }
    // A: 32 f32 per thread -> bf16 (two halves of 16 to cap live VGPRs)
    const float* srcA = A + (size_t)(m0 + rowA) * 256 + i * 64 + hA * 32;
    bf16* dstA = &As[hA][rowA * 32];
#pragma unroll
    for (int half = 0; half < 2; ++half) {
      const float4 f0 = *(const float4*)(srcA + half * 16 + 0);
      const float4 f1 = *(const float4*)(srcA + half * 16 + 4);
      const float4 f2 = *(const float4*)(srcA + half * 16 + 8);
      const float4 f3 = *(const float4*)(srcA + half * 16 + 12);
      bf16x8 b0, b1;
      b0[0] = (bf16)f0.x; b0[1] = (bf16)f0.y; b0[2] = (bf16)f0.z; b0[3] = (bf16)f0.w;
      b0[4] = (bf16)f1.x; b0[5] = (bf16)f1.y; b0[6] = (bf16)f1.z; b0[7] = (bf16)f1.w;
      b1[0] = (bf16)f2.x; b1[1] = (bf16)f2.y; b1[2] = (bf16)f2.z; b1[3] = (bf16)f2.w;
      b1[4] = (bf16)f3.x; b1[5] = (bf16)f3.y; b1[6] = (bf16)f3.z; b1[7] = (bf16)f3.w;
      *(bf16x8*)&dstA[half * 16] = b0;
      *(bf16x8*)&dstA[half * 16 + 8] = b1;
    }
    __syncthreads();
#pragma unroll
    for (int ks = 0; ks < 2; ++ks) {
      bf16x8 av[4], bvf[4];
#pragma unroll
      for (int t = 0; t < 4; ++t)
        av[t] = *(const bf16x8*)&As[ks][(mw + t * 16 + lm) * 32 + lq * 8];
#pragma unroll
      for (int t = 0; t < 4; ++t)
        bvf[t] = *(const bf16x8*)&Bs[ks][(nw + t * 16 + lm) * 32 + lq * 8];
#pragma unroll
      for (int a = 0; a < 4; ++a)
#pragma unroll
        for (int b = 0; b < 4; ++b)
          acc[a][b] = __builtin_amdgcn_mfma_f32_16x16x32_bf16(av[a], bvf[b], acc[a][b], 0, 0, 0);
    }
    __syncthreads();
  }

  // Epilogue. C layout: col = lane&15, row = (lane>>4)*4 + reg.
#pragma unroll
  for (int a = 0; a < 4; ++a)
#pragma unroll
    for (int b = 0; b < 4; ++b) {
      const int nglob = nb * 128 + nw + b * 16 + lm;
      bf16* op; const float* bp; int nc;
      if (nglob < 256)      { op = qp; nc = nglob;       bp = bq; }
      else if (nglob < 512) { op = kp; nc = nglob - 256; bp = bk; }
      else                  { op = vp; nc = nglob - 512; bp = bvv; }
      const float bval = bp[nc];
#pragma unroll
      for (int r = 0; r < 4; ++r) {
        const int mg = m0 + mw + a * 16 + lq * 4 + r;
        op[(size_t)mg * 256 + nc] = (bf16)(acc[a][b][r] + bval);
      }
    }
}

// ---------------------------------------------------------------------------
// Output projection: exact 2-term as K=512 GEMM (iters 0-3 hi, 4-7 lo; A re-read).
// A = ao (bf16) via gll16; B via gll16 from packO. Out f32 + bias.
// ---------------------------------------------------------------------------
__global__ __launch_bounds__(256, 3) void k_oproj(
    const bf16* __restrict__ ao, const bf16* __restrict__ packO,
    const float* __restrict__ bo, float* __restrict__ out) {
  __shared__ __align__(16) bf16 As[2][128 * 32];
  __shared__ __align__(16) bf16 Bs[2][128 * 32];

  const int g = blockIdx.x, xcd = g & 7, s = g >> 3;
  const int nb = s & 1, mh = s >> 1;
  const int m0 = (mh * 8 + xcd) * 128;

  const int tid = threadIdx.x, lane = tid & 63, wave = tid >> 6;
  const int mw = (wave >> 1) * 64, nw = (wave & 1) * 64;
  const int lm = lane & 15, lq = lane >> 4;

  f32x4 acc[4][4];
#pragma unroll
  for (int a = 0; a < 4; ++a)
#pragma unroll
    for (int b = 0; b < 4; ++b) acc[a][b] = (f32x4)0.0f;

  const bf16* pbase = packO + (size_t)nb * 8 * 8192;

  for (int i = 0; i < 8; ++i) {
    const int kA = (i & 3) * 64;
#pragma unroll
    for (int u = 0; u < 4; ++u) {
      const int c = u * 256 + tid;
      const int h = c >> 9, r2 = c & 511;
      const int row = r2 >> 2, kg = c & 3;
      bf16* dstB = (u < 2) ? &Bs[0][c * 8] : &Bs[1][(c - 512) * 8];
      gll16(pbase + (size_t)i * 8192 + c * 8, dstB);
      bf16* dstA = (u < 2) ? &As[0][r2 * 8] : &As[1][r2 * 8];
      gll16(ao + (size_t)(m0 + row) * 256 + kA + h * 32 + kg * 8, dstA);
    }
    __syncthreads();
#pragma unroll
    for (int ks = 0; ks < 2; ++ks) {
      bf16x8 av[4], bvf[4];
#pragma unroll
      for (int t = 0; t < 4; ++t)
        av[t] = *(const bf16x8*)&As[ks][(mw + t * 16 + lm) * 32 + lq * 8];
#pragma unroll
      for (int t = 0; t < 4; ++t)
        bvf[t] = *(const bf16x8*)&Bs[ks][(nw + t * 16 + lm) * 32 + lq * 8];
#pragma unroll
      for (int a = 0; a < 4; ++a)
#pragma unroll
        for (int b = 0; b < 4; ++b)
          acc[a][b] = __builtin_amdgcn_mfma_f32_16x16x32_bf16(av[a], bvf[b], acc[a][b], 0, 0, 0);
    }
    __syncthreads();
  }

#pragma unroll
  for (int a = 0; a < 4; ++a)
#pragma unroll
    for (int b = 0; b < 4; ++b) {
      const int nglob = nb * 128 + nw + b * 16 + lm;
      const float bval = bo[nglob];
#pragma unroll
      for (int r = 0; r < 4; ++r) {
        const int mg = m0 + mw + a * 16 + lq * 4 + r;
        out[(size_t)mg * 256 + nglob] = acc[a][b][r] + bval;
      }
    }
}

// ---------------------------------------------------------------------------
// Windowed attention (unchanged; will profile this round).
// ---------------------------------------------------------------------------
__global__ __launch_bounds__(256) void k_attn(
    const bf16* __restrict__ qp, const bf16* __restrict__ kp,
    const bf16* __restrict__ vp, bf16* __restrict__ ao) {
  __shared__ __align__(16) bf16 smem[3 * 64 * 136];
  bf16* Qs = smem;
  bf16* Ks = smem + 64 * 136;
  bf16* Vs = smem + 2 * 64 * 136;
  bf16* Ps = smem;
  bf16* Os = Vs;

  const int tid = threadIdx.x;
  const int lane = tid & 63;
  const int hl = tid >> 6;
  const int bw = blockIdx.x;
  const int b = bw >> 8;
  const int w = bw & 255;
  const int wy = w >> 4, wx = w & 15;
  const int ch0 = blockIdx.y * 128;

#pragma unroll
  for (int i = 0; i < 4; ++i) {
    const int c = i * 256 + tid;
    const int t = c >> 4;
    const int off = (c & 15) * 8;
    const int ty = t >> 3, tx = t & 7;
    const size_t gr = ((size_t)(b * 128 + wy * 8 + ty)) * 128 + wx * 8 + tx;
    const size_t gi = gr * 256 + ch0 + off;
    const int li = t * 136 + off;
    *(uint4*)&Qs[li] = *(const uint4*)&qp[gi];
    *(uint4*)&Ks[li] = *(const uint4*)&kp[gi];
    *(uint4*)&Vs[li] = *(const uint4*)&vp[gi];
  }
  __syncthreads();

  const int chh = hl * 32;
  const int lm = lane & 15;
  const int lq = lane >> 4;

  bf16x8 qa[4], kb[4];
#pragma unroll
  for (int t = 0; t < 4; ++t)
    qa[t] = *(const bf16x8*)&Qs[(t * 16 + lm) * 136 + chh + lq * 8];
#pragma unroll
  for (int t = 0; t < 4; ++t)
    kb[t] = *(const bf16x8*)&Ks[(t * 16 + lm) * 136 + chh + lq * 8];

  f32x4 s[4][4];
#pragma unroll
  for (int i = 0; i < 4; ++i)
#pragma unroll
    for (int j = 0; j < 4; ++j) s[i][j] = (f32x4)0.0f;
#pragma unroll
  for (int i = 0; i < 4; ++i)
#pragma unroll
    for (int j = 0; j < 4; ++j)
      s[i][j] = __builtin_amdgcn_mfma_f32_16x16x32_bf16(qa[i], kb[j], s[i][j], 0, 0, 0);

  const float scale = 0.17677669529663687f;
  float rl[4][4];
#pragma unroll
  for (int mt = 0; mt < 4; ++mt) {
#pragma unroll
    for (int r = 0; r < 4; ++r) {
      float mx = fmaxf(fmaxf(s[mt][0][r], s[mt][1][r]), fmaxf(s[mt][2][r], s[mt][3][r]));
      mx = fmaxf(mx, __shfl_xor(mx, 1));
      mx = fmaxf(mx, __shfl_xor(mx, 2));
      mx = fmaxf(mx, __shfl_xor(mx, 4));
      mx = fmaxf(mx, __shfl_xor(mx, 8));
      float sum = 0.f;
#pragma unroll
      for (int nt = 0; nt < 4; ++nt) {
        const float p = __expf((s[mt][nt][r] - mx) * scale);
        s[mt][nt][r] = p;
        sum += p;
      }
      sum += __shfl_xor(sum, 1);
      sum += __shfl_xor(sum, 2);
      sum += __shfl_xor(sum, 4);
      sum += __shfl_xor(sum, 8);
      rl[mt][r] = 1.0f / sum;
    }
  }

  __syncthreads();

  bf16* Ph = Ps + hl * 4096;
#pragma unroll
  for (int mt = 0; mt < 4; ++mt)
#pragma unroll
    for (int nt = 0; nt < 4; ++nt)
#pragma unroll
      for (int r = 0; r < 4; ++r) {
        const int qrow = mt * 16 + lq * 4 + r;
        const int kcol = nt * 16 + lm;
        Ph[qrow * 64 + (((kcol >> 3) ^ (qrow & 7)) << 3) + (kcol & 7)] = (bf16)s[mt][nt][r];
      }

  f32x4 o[4][2];
#pragma unroll
  for (int i = 0; i < 4; ++i) { o[i][0] = (f32x4)0.0f; o[i][1] = (f32x4)0.0f; }
#pragma unroll
  for (int ks = 0; ks < 2; ++ks) {
    bf16x8 pa[4];
#pragma unroll
    for (int mt = 0; mt < 4; ++mt) {
      const int qrow = mt * 16 + lm;
      const int gsel = ks * 4 + lq;
      pa[mt] = *(const bf16x8*)&Ph[qrow * 64 + ((gsel ^ (qrow & 7)) << 3)];
    }
    bf16x8 vbf[2];
#pragma unroll
    for (int ntd = 0; ntd < 2; ++ntd) {
      const int d = ntd * 16 + lm;
      bf16x8 tv;
#pragma unroll
      for (int j = 0; j < 8; ++j)
        tv[j] = Vs[(ks * 32 + lq * 8 + j) * 136 + chh + d];
      vbf[ntd] = tv;
    }
#pragma unroll
    for (int mt = 0; mt < 4; ++mt)
#pragma unroll
      for (int ntd = 0; ntd < 2; ++ntd)
        o[mt][ntd] = __builtin_amdgcn_mfma_f32_16x16x32_bf16(pa[mt], vbf[ntd], o[mt][ntd], 0, 0, 0);
  }

  __syncthreads();

#pragma unroll
  for (int mt = 0; mt < 4; ++mt)
#pragma unroll
    for (int ntd = 0; ntd < 2; ++ntd)
#pragma unroll
      for (int r = 0; r < 4; ++r) {
        const int qrow = mt * 16 + lq * 4 + r;
        const int d = ntd * 16 + lm;
        Os[qrow * 136 + chh + d] = (bf16)(o[mt][ntd][r] * rl[mt][r]);
      }
  __syncthreads();

#pragma unroll
  for (int i = 0; i < 4; ++i) {
    const int c = i * 256 + tid;
    const int t = c >> 4;
    const int off = (c & 15) * 8;
    const int ty = t >> 3, tx = t & 7;
    const size_t gr = ((size_t)(b * 128 + wy * 8 + ty)) * 128 + wx * 8 + tx;
    *(uint4*)&ao[gr * 256 + ch0 + off] = *(const uint4*)&Os[t * 136 + off];
  }
}

// ---------------------------------------------------------------------------
extern "C" void kernel_launch(void* const* d_in, const int* in_sizes, int n_in,
                              void* d_out, int out_size, void* d_ws, size_t ws_size,
                              hipStream_t stream) {
  const float* q  = (const float*)d_in[0];
  const float* kv = (const float*)d_in[1];
  const float* Wq = (const float*)d_in[2];
  const float* bq = (const float*)d_in[3];
  const float* Wk = (const float*)d_in[4];
  const float* bk = (const float*)d_in[5];
  const float* Wv = (const float*)d_in[6];
  const float* bv = (const float*)d_in[7];
  const float* Wo = (const float*)d_in[8];
  const float* bo = (const float*)d_in[9];
  float* out = (float*)d_out;

  char* ws = (char*)d_ws;
  bf16* packQ = (bf16*)(ws + 0);        // 393216 B
  bf16* packO = (bf16*)(ws + 393216);   // 262144 B
  const size_t PLANE = (size_t)65536 * 256 * 2;
  bf16* qp = (bf16*)(ws + 1048576);
  bf16* kp = (bf16*)(ws + 1048576 + PLANE);
  bf16* vp = (bf16*)(ws + 1048576 + 2 * PLANE);
  bf16* ao = (bf16*)(ws + 1048576 + 3 * PLANE);
  if (ws_size < 1048576 + 4 * PLANE) return;

  k_prep<<<dim3(256, 5), 256, 0, stream>>>(Wq, Wk, Wv, Wo, packQ, packO);
  k_qkv<<<3072, 256, 0, stream>>>(q, kv, packQ, bq, bk, bv, qp, kp, vp);
  k_attn<<<dim3(1024, 2), 256, 0, stream>>>(qp, kp, vp, ao);
  k_oproj<<<1024, 256, 0, stream>>>(ao, packO, bo, out);
}